// Round 10
// baseline (171.660 us; speedup 1.0000x reference)
//
#include <hip/hip_runtime.h>
#include <hip/hip_bf16.h>
#include <hip/hip_fp8.h>

// ---------------------------------------------------------------------------
// Triplet loss via ONE 4096^2 sq-distance GEMM in MX-fp8 (scale=1):
//   G[i,j] = ||i_f[i]||^2 + ||v_f[j]+eps||^2 - 2 q(i_f[i]).q(v_f[j])
//   loss_i: per row i (anchor i_f[i]); loss_v: per col j (anchor v_f[j]).
// Norms exact f32; cross term fp8-e4m3 (validated: absmax 0 in R9).
// 8 waves (2M x 4N), wave tile 128x64, mfma_scale_f32_32x32x64_f8f6f4:
// one MFMA spans the whole BK=64 K-tile -> 2 phases/K-tile:
//   ph0: ds_read aF[0..3]+bF0 ; BAR ; stage Ah0,Ah1(t+2)->cur ; 4 MFMA ; BAR
//   ph1: ds_read bF1          ; BAR ; stage Bh0,Bh1(t+2)->cur ; 4 MFMA ;
//        vmcnt(4) (drains t+1, keeps t+2's 4 in flight) ; BAR
// LDS swizzle: 16B chunk ^= (row&3)^((row>>2)&3); linear gload_lds dest,
// pre-swizzled global source, same involution on ds_read.
// R10 fix: __launch_bounds__(512,1) -- (512,2)'s 128-VGPR cap spilled the
// 128-float accumulator to scratch (R9: 247MB WRITE_SIZE, MfmaUtil 3.9%).
// ---------------------------------------------------------------------------

#define MDIM 4096
#define KDIM 1024
#define NT   16      // K-tiles of 64

typedef __attribute__((ext_vector_type(16))) float f32x16;
typedef __attribute__((ext_vector_type(8)))  int   i32x8;
typedef __attribute__((ext_vector_type(4)))  int   i32x4;

__device__ __forceinline__ void gload16(const void* g, void* l) {
  __builtin_amdgcn_global_load_lds(
      (const __attribute__((address_space(1))) void*)g,
      (__attribute__((address_space(3))) void*)l,
      16, 0, 0);
}

__device__ __forceinline__ unsigned char f2e4m3(float x) {
  __hip_fp8_e4m3 q(x);           // OCP e4m3fn on gfx950, HW RNE convert
  return (unsigned char)q.__x;
}

#define BAR() do { asm volatile("" ::: "memory"); \
                   __builtin_amdgcn_s_barrier();  \
                   asm volatile("" ::: "memory"); } while (0)

// --- prep: wave-per-row (FULL 1024 dims), f32 -> fp8 + exact f32 norms -----
__global__ __launch_bounds__(256) void prep_kernel(
    const float* __restrict__ vf, const float* __restrict__ iff,
    unsigned char* __restrict__ vb8, unsigned char* __restrict__ ib8,
    float* __restrict__ ni, float* __restrict__ nvp,
    int* __restrict__ same_sq, int* __restrict__ diff_sq,
    float* __restrict__ out) {
  const int wid = blockIdx.x * 4 + (threadIdx.x >> 6);  // 0..8191, wave = row
  const int lane = threadIdx.x & 63;
  const int mat = wid >> 12;              // 0 = v_f, 1 = i_f
  const int row = wid & 4095;
  const float* X = mat ? iff : vf;
  unsigned char* Xb = mat ? ib8 : vb8;

  const float4* xr4 = (const float4*)(X + (size_t)row * KDIM);
  uchar4* xb4 = (uchar4*)(Xb + (size_t)row * KDIM);

  float s = 0.0f;
#pragma unroll
  for (int it = 0; it < 4; ++it) {        // 4 x 64 lanes x 4 floats = 1024
    const int idx = it * 64 + lane;
    float4 v = xr4[idx];
    if (mat) {
      s += v.x * v.x + v.y * v.y + v.z * v.z + v.w * v.w;
    } else {
      float ex = v.x + 1e-6f, ey = v.y + 1e-6f, ez = v.z + 1e-6f, ew = v.w + 1e-6f;
      s += ex * ex + ey * ey + ez * ez + ew * ew;
    }
    uchar4 o;
    o.x = f2e4m3(v.x); o.y = f2e4m3(v.y); o.z = f2e4m3(v.z); o.w = f2e4m3(v.w);
    xb4[idx] = o;
  }
  for (int off = 32; off; off >>= 1) s += __shfl_down(s, off);
  if (lane == 0) {
    if (mat) ni[row] = s; else nvp[row] = s;
  }

  // fused init (first 32 blocks cover the 8192-entry reduce buffers)
  const int gi = blockIdx.x * 256 + threadIdx.x;
  if (gi < 2 * MDIM) {
    same_sq[gi] = 0;             // sq >= 0: 0 is max-identity
    diff_sq[gi] = 0x7F800000;    // +inf
  }
  if (gi == 0) out[0] = 0.0f;
}

// --- fused 256x256 MX-fp8 GEMM + distance + masked row AND col max/min -----
// A = i_f (rows), B = v_f (cols; +eps norms).
__global__ __launch_bounds__(512, 1) void tri_gemm(
    const unsigned char* __restrict__ vb8, const unsigned char* __restrict__ ib8,
    const float* __restrict__ ni, const float* __restrict__ nvp,
    const int* __restrict__ y,
    int* __restrict__ same_sq, int* __restrict__ diff_sq) {
  // K-tile buffer: [256 rows][64 k] fp8, row = 64 B, 4 chunks of 16 B.
  __shared__ unsigned char Abuf[2][256][64];   // 32 KiB
  __shared__ unsigned char Bbuf[2][256][64];   // 32 KiB
  __shared__ int   yrow[256], ycol[256];
  __shared__ float nAr[256], nBc[256];

  const unsigned char* Amat = ib8;
  const unsigned char* Bmat = vb8;

  const int row0 = blockIdx.y * 256;
  const int col0 = blockIdx.x * 256;

  const int t = threadIdx.x;
  const int w = t >> 6, lane = t & 63;
  const int l32 = lane & 31, hi = lane >> 5;
  const int wr = w >> 2, wc = w & 3;            // 2 x 4 waves -> 128 x 64 tile

  auto swz = [](int row) { return (row & 3) ^ ((row >> 2) & 3); };

  // stage one half-tile (128 rows x 64 B = 8 KB) = 1 gload16 per thread
  auto stage = [&](const unsigned char* __restrict__ X, int tile0,
                   unsigned char (&buf)[256][64], int h, int k0s) {
    const int row = h * 128 + (t >> 2);
    const int cD = t & 3;
    const unsigned char* src =
        X + (size_t)(tile0 + row) * KDIM + k0s + ((cD ^ swz(row)) << 4);
    gload16(src, &buf[h * 128 + (w << 4)][0]);   // wave-uniform linear dest
  };
  // 32x32x64 f8 operand: lane holds row/col (lane&31), k bytes [hi*32, hi*32+32)
  auto ldA = [&](int c, int R) -> i32x8 {
    const int row = wr * 128 + R * 32 + l32;
    const int s = swz(row);
    const i32x4 lo = *(const i32x4*)&Abuf[c][row][((2 * hi) ^ s) << 4];
    const i32x4 hi4 = *(const i32x4*)&Abuf[c][row][((2 * hi + 1) ^ s) << 4];
    i32x8 r;
    r[0] = lo[0]; r[1] = lo[1]; r[2] = lo[2]; r[3] = lo[3];
    r[4] = hi4[0]; r[5] = hi4[1]; r[6] = hi4[2]; r[7] = hi4[3];
    return r;
  };
  auto ldB = [&](int c, int Cb) -> i32x8 {
    const int col = wc * 64 + Cb * 32 + l32;
    const int s = swz(col);
    const i32x4 lo = *(const i32x4*)&Bbuf[c][col][((2 * hi) ^ s) << 4];
    const i32x4 hi4 = *(const i32x4*)&Bbuf[c][col][((2 * hi + 1) ^ s) << 4];
    i32x8 r;
    r[0] = lo[0]; r[1] = lo[1]; r[2] = lo[2]; r[3] = lo[3];
    r[4] = hi4[0]; r[5] = hi4[1]; r[6] = hi4[2]; r[7] = hi4[3];
    return r;
  };

  // ---- prologue: tile 0 fully + tile 1 fully-in-flight; labels/norms ----
  stage(Amat, row0, Abuf[0], 0, 0);
  stage(Amat, row0, Abuf[0], 1, 0);
  stage(Bmat, col0, Bbuf[0], 0, 0);
  stage(Bmat, col0, Bbuf[0], 1, 0);
  stage(Amat, row0, Abuf[1], 0, 64);
  stage(Amat, row0, Abuf[1], 1, 64);
  stage(Bmat, col0, Bbuf[1], 0, 64);
  stage(Bmat, col0, Bbuf[1], 1, 64);
  if (t < 256) {
    yrow[t] = y[row0 + t];
    nAr[t] = ni[row0 + t];
  } else {
    const int c = t - 256;
    ycol[c] = y[col0 + c];
    nBc[c] = nvp[col0 + c];
  }
  // drain tile 0; keep tile 1's 4 half-stages in flight
  asm volatile("s_waitcnt vmcnt(4) lgkmcnt(0)" ::: "memory");
  BAR();

  f32x16 acc[4][2] = {};
  i32x8 aF[4], bF0, bF1;

// One K-tile = 2 phases. C: buffer of tile t (literal 0/1); K2: k-offset of
// tile t+2 (staged into buf C after its reads retire).
#define DO_TILE(C, K2)                                                         \
  do {                                                                         \
    /* ph0: read all A frags + bF0 */                                          \
    _Pragma("unroll") for (int R = 0; R < 4; ++R) aF[R] = ldA(C, R);           \
    bF0 = ldB(C, 0);                                                           \
    BAR();                                                                     \
    stage(Amat, row0, Abuf[C], 0, (K2));   /* A[C] fully read by all waves */  \
    stage(Amat, row0, Abuf[C], 1, (K2));                                       \
    __builtin_amdgcn_s_setprio(1);                                             \
    _Pragma("unroll") for (int R = 0; R < 4; ++R)                              \
      acc[R][0] = __builtin_amdgcn_mfma_scale_f32_32x32x64_f8f6f4(             \
          aF[R], bF0, acc[R][0], 0, 0, 0, 0x7F7F7F7F, 0, 0x7F7F7F7F);          \
    __builtin_amdgcn_s_setprio(0);                                             \
    BAR();                                                                     \
    /* ph1: read bF1 */                                                        \
    bF1 = ldB(C, 1);                                                           \
    BAR();                                                                     \
    stage(Bmat, col0, Bbuf[C], 0, (K2));   /* B[C] fully read by all waves */  \
    stage(Bmat, col0, Bbuf[C], 1, (K2));                                       \
    __builtin_amdgcn_s_setprio(1);                                             \
    _Pragma("unroll") for (int R = 0; R < 4; ++R)                              \
      acc[R][1] = __builtin_amdgcn_mfma_scale_f32_32x32x64_f8f6f4(             \
          aF[R], bF1, acc[R][1], 0, 0, 0, 0x7F7F7F7F, 0, 0x7F7F7F7F);          \
    __builtin_amdgcn_s_setprio(0);                                             \
    asm volatile("s_waitcnt vmcnt(4)" ::: "memory");                           \
    BAR();                                                                     \
  } while (0)

  for (int kt = 0; kt < NT; kt += 2) {
    const int kb = ((kt + 2) & (NT - 1)) * 64;
    const int kc = ((kt + 3) & (NT - 1)) * 64;
    DO_TILE(0, kb);   // even tile lives in buf 0
    DO_TILE(1, kc);   // odd tile lives in buf 1
  }
#undef DO_TILE
  asm volatile("s_waitcnt vmcnt(0)" ::: "memory");

  // ---- epilogue: sq + mask; row-reduce -> loss_i, col-reduce -> loss_v ----
  // C/D 32x32: col = lane&31, row = (reg&3) + 8*(reg>>2) + 4*(lane>>5)
  const int rbase0 = row0;          // dir0: anchors i_f, indexed by row
  const int rbase1 = MDIM + col0;   // dir1: anchors v_f, indexed by col
  const float INF = __int_as_float(0x7F800000);

  float cs[2] = {0.0f, 0.0f};
  float cd[2] = {INF, INF};

#pragma unroll
  for (int R = 0; R < 4; ++R) {
#pragma unroll
    for (int g = 0; g < 16; ++g) {
      const int row_loc = wr * 128 + R * 32 + (g & 3) + 8 * (g >> 2) + 4 * hi;
      const float na = nAr[row_loc];
      const int yl = yrow[row_loc];
      float smax = 0.0f;
      float dmin = INF;
#pragma unroll
      for (int Cb = 0; Cb < 2; ++Cb) {
        const int col_loc = wc * 64 + Cb * 32 + l32;
        const float sq = fmaxf(na + nBc[col_loc] - 2.0f * acc[R][Cb][g], 0.0f);
        if (ycol[col_loc] == yl) {
          smax = fmaxf(smax, sq);
          cs[Cb] = fmaxf(cs[Cb], sq);
        } else {
          dmin = fminf(dmin, sq);
          cd[Cb] = fminf(cd[Cb], sq);
        }
      }
#pragma unroll
      for (int off = 1; off < 32; off <<= 1) {   // reduce within 32-lane half
        smax = fmaxf(smax, __shfl_xor(smax, off));
        dmin = fminf(dmin, __shfl_xor(dmin, off));
      }
      if (l32 == g) {   // spread atomics across lanes; both hi-halves write
        // nonneg floats: int compare == float compare -> order-independent
        atomicMax(&same_sq[rbase0 + row_loc], __float_as_int(smax));
        atomicMin(&diff_sq[rbase0 + row_loc], __float_as_int(dmin));
      }
    }
  }
  // col reduce: merge hi-halves (rows of each half), lanes hi==0 publish
#pragma unroll
  for (int Cb = 0; Cb < 2; ++Cb) {
    float s = cs[Cb], d = cd[Cb];
    s = fmaxf(s, __shfl_xor(s, 32));
    d = fminf(d, __shfl_xor(d, 32));
    if (hi == 0) {
      const int col_loc = wc * 64 + Cb * 32 + l32;
      atomicMax(&same_sq[rbase1 + col_loc], __float_as_int(s));
      atomicMin(&diff_sq[rbase1 + col_loc], __float_as_int(d));
    }
  }
}

// --- finalize: sqrt, relu, sum ---------------------------------------------
__global__ __launch_bounds__(256) void finalize_kernel(
    const int* __restrict__ same_sq, const int* __restrict__ diff_sq,
    float* __restrict__ out) {
  const int i = blockIdx.x * 256 + threadIdx.x;  // 8192 total
  const float sm = sqrtf(__int_as_float(same_sq[i]));
  const float dm = sqrtf(__int_as_float(diff_sq[i]));  // +inf if no diff label
  float l = fmaxf(sm - dm + 1.2f, 0.0f);
  for (int off = 32; off; off >>= 1) l += __shfl_down(l, off);
  __shared__ float part[4];
  const int w = threadIdx.x >> 6, lane = threadIdx.x & 63;
  if (lane == 0) part[w] = l;
  __syncthreads();
  if (threadIdx.x == 0) atomicAdd(out, part[0] + part[1] + part[2] + part[3]);
}

extern "C" void kernel_launch(void* const* d_in, const int* in_sizes, int n_in,
                              void* d_out, int out_size, void* d_ws, size_t ws_size,
                              hipStream_t stream) {
  const float* vf = (const float*)d_in[0];
  const float* iff = (const float*)d_in[1];
  const int* y = (const int*)d_in[2];
  float* out = (float*)d_out;

  char* ws = (char*)d_ws;
  unsigned char* vb8 = (unsigned char*)ws;                        // 4 MB
  unsigned char* ib8 = (unsigned char*)(ws + (4u << 20));         // 4 MB
  float* nv  = (float*)(ws + (8u << 20));
  float* ni  = nv + 4096;
  float* nvp = nv + 2 * 4096;
  int* same_sq = (int*)(nv + 4 * 4096);                           // [2][4096]
  int* diff_sq = same_sq + 2 * 4096;                              // [2][4096]

  prep_kernel<<<2048, 256, 0, stream>>>(vf, iff, vb8, ib8, ni, nvp,
                                        same_sq, diff_sq, out);
  tri_gemm<<<dim3(16, 16), 512, 0, stream>>>(vb8, ib8, ni, nvp, y,
                                             same_sq, diff_sq);
  finalize_kernel<<<32, 256, 0, stream>>>(same_sq, diff_sq, out);
}

// Round 11
// 59.772 us; speedup vs baseline: 2.8719x; 2.8719x over previous
//
#include <hip/hip_runtime.h>
#include <hip/hip_bf16.h>
#include <hip/hip_fp8.h>

// ---------------------------------------------------------------------------
// Triplet loss via ONE 4096^2 sq-distance GEMM in MX-fp8 (scale=1):
//   G[i,j] = ||i_f[i]||^2 + ||v_f[j]+eps||^2 - 2 q(i_f[i]).q(v_f[j])
//   loss_i: per row i (anchor i_f[i]); loss_v: per col j (anchor v_f[j]).
// Norms exact f32; cross term fp8-e4m3 (numerics validated: absmax 0, R9/R10).
// R11: block tile 256x128, 8 waves 4Mx2N -> 64x64/wave, acc = 64 VGPR
// (R9/R10 spilled: 128-float acc vs 128-VGPR cap). LDS 51KB -> 2 blocks/CU
// = independent TLP. 2 phases per K-tile of 64:
//   ph0: ds_read aF[0..1]+bF ; BAR ; 2 MFMA ; BAR
//   ph1: ds_read bF' ; stage Ah0,Ah1(t+2)->C (A[C] barrier-retired) ; BAR ;
//        2 MFMA ; stage B(t+2)->C ; vmcnt(3) (keeps t+2's 3 in flight) ; BAR
// LDS swizzle: 16B chunk ^= (row&3)^((row>>2)&3); linear gload_lds dest,
// pre-swizzled global source, same involution on ds_read.
// ---------------------------------------------------------------------------

#define MDIM 4096
#define KDIM 1024
#define NT   16      // K-tiles of 64

typedef __attribute__((ext_vector_type(16))) float f32x16;
typedef __attribute__((ext_vector_type(8)))  int   i32x8;
typedef __attribute__((ext_vector_type(4)))  int   i32x4;

__device__ __forceinline__ void gload16(const void* g, void* l) {
  __builtin_amdgcn_global_load_lds(
      (const __attribute__((address_space(1))) void*)g,
      (__attribute__((address_space(3))) void*)l,
      16, 0, 0);
}

__device__ __forceinline__ unsigned char f2e4m3(float x) {
  __hip_fp8_e4m3 q(x);           // OCP e4m3fn on gfx950, HW RNE convert
  return (unsigned char)q.__x;
}

#define BAR() do { asm volatile("" ::: "memory"); \
                   __builtin_amdgcn_s_barrier();  \
                   asm volatile("" ::: "memory"); } while (0)

// --- prep: wave-per-row (FULL 1024 dims), f32 -> fp8 + exact f32 norms -----
__global__ __launch_bounds__(256) void prep_kernel(
    const float* __restrict__ vf, const float* __restrict__ iff,
    unsigned char* __restrict__ vb8, unsigned char* __restrict__ ib8,
    float* __restrict__ ni, float* __restrict__ nvp,
    int* __restrict__ same_sq, int* __restrict__ diff_sq,
    float* __restrict__ out) {
  const int wid = blockIdx.x * 4 + (threadIdx.x >> 6);  // 0..8191, wave = row
  const int lane = threadIdx.x & 63;
  const int mat = wid >> 12;              // 0 = v_f, 1 = i_f
  const int row = wid & 4095;
  const float* X = mat ? iff : vf;
  unsigned char* Xb = mat ? ib8 : vb8;

  const float4* xr4 = (const float4*)(X + (size_t)row * KDIM);
  uchar4* xb4 = (uchar4*)(Xb + (size_t)row * KDIM);

  float s = 0.0f;
#pragma unroll
  for (int it = 0; it < 4; ++it) {        // 4 x 64 lanes x 4 floats = 1024
    const int idx = it * 64 + lane;
    float4 v = xr4[idx];
    if (mat) {
      s += v.x * v.x + v.y * v.y + v.z * v.z + v.w * v.w;
    } else {
      float ex = v.x + 1e-6f, ey = v.y + 1e-6f, ez = v.z + 1e-6f, ew = v.w + 1e-6f;
      s += ex * ex + ey * ey + ez * ez + ew * ew;
    }
    uchar4 o;
    o.x = f2e4m3(v.x); o.y = f2e4m3(v.y); o.z = f2e4m3(v.z); o.w = f2e4m3(v.w);
    xb4[idx] = o;
  }
  for (int off = 32; off; off >>= 1) s += __shfl_down(s, off);
  if (lane == 0) {
    if (mat) ni[row] = s; else nvp[row] = s;
  }

  // fused init (first 32 blocks cover the 8192-entry reduce buffers)
  const int gi = blockIdx.x * 256 + threadIdx.x;
  if (gi < 2 * MDIM) {
    same_sq[gi] = 0;             // sq >= 0: 0 is max-identity
    diff_sq[gi] = 0x7F800000;    // +inf
  }
  if (gi == 0) out[0] = 0.0f;
}

// --- fused 256x128 MX-fp8 GEMM + distance + masked row AND col max/min -----
// A = i_f (rows), B = v_f (cols; +eps norms).
__global__ __launch_bounds__(512, 4) void tri_gemm(
    const unsigned char* __restrict__ vb8, const unsigned char* __restrict__ ib8,
    const float* __restrict__ ni, const float* __restrict__ nvp,
    const int* __restrict__ y,
    int* __restrict__ same_sq, int* __restrict__ diff_sq) {
  // K-tile buffers: row = 64 B fp8 = 4 chunks of 16 B.
  __shared__ unsigned char Abuf[2][256][64];   // 32 KiB
  __shared__ unsigned char Bbuf[2][128][64];   // 16 KiB
  __shared__ int   yrow[256], ycol[128];
  __shared__ float nAr[256], nBc[128];

  const unsigned char* Amat = ib8;
  const unsigned char* Bmat = vb8;

  const int row0 = blockIdx.y * 256;
  const int col0 = blockIdx.x * 128;

  const int t = threadIdx.x;
  const int w = t >> 6, lane = t & 63;
  const int l32 = lane & 31, hi = lane >> 5;
  const int wr = w >> 1, wc = w & 1;            // 4 x 2 waves -> 64 x 64 tile

  auto swz = [](int row) { return (row & 3) ^ ((row >> 2) & 3); };

  // stage one 128-row unit (128 x 64 B = 8 KB) = 1 gload16 per thread
  auto stageA = [&](unsigned char (&buf)[256][64], int h, int k0s) {
    const int row = h * 128 + (t >> 2);
    const int cD = t & 3;
    const unsigned char* src =
        Amat + (size_t)(row0 + row) * KDIM + k0s + ((cD ^ swz(row)) << 4);
    gload16(src, &buf[h * 128 + (w << 4)][0]);   // wave-uniform linear dest
  };
  auto stageB = [&](unsigned char (&buf)[128][64], int k0s) {
    const int row = t >> 2;
    const int cD = t & 3;
    const unsigned char* src =
        Bmat + (size_t)(col0 + row) * KDIM + k0s + ((cD ^ swz(row)) << 4);
    gload16(src, &buf[w << 4][0]);
  };
  // 32x32x64 f8 operand: lane holds row/col (lane&31), k bytes [hi*32,+32)
  auto ldA = [&](int c, int R) -> i32x8 {
    const int row = wr * 64 + R * 32 + l32;
    const int s = swz(row);
    const i32x4 lo = *(const i32x4*)&Abuf[c][row][((2 * hi) ^ s) << 4];
    const i32x4 hi4 = *(const i32x4*)&Abuf[c][row][((2 * hi + 1) ^ s) << 4];
    i32x8 r;
    r[0] = lo[0]; r[1] = lo[1]; r[2] = lo[2]; r[3] = lo[3];
    r[4] = hi4[0]; r[5] = hi4[1]; r[6] = hi4[2]; r[7] = hi4[3];
    return r;
  };
  auto ldB = [&](int c, int Cb) -> i32x8 {
    const int col = wc * 64 + Cb * 32 + l32;
    const int s = swz(col);
    const i32x4 lo = *(const i32x4*)&Bbuf[c][col][((2 * hi) ^ s) << 4];
    const i32x4 hi4 = *(const i32x4*)&Bbuf[c][col][((2 * hi + 1) ^ s) << 4];
    i32x8 r;
    r[0] = lo[0]; r[1] = lo[1]; r[2] = lo[2]; r[3] = lo[3];
    r[4] = hi4[0]; r[5] = hi4[1]; r[6] = hi4[2]; r[7] = hi4[3];
    return r;
  };

  // ---- prologue: tiles 0 and 1 in flight; labels/norms ----
  stageA(Abuf[0], 0, 0);
  stageA(Abuf[0], 1, 0);
  stageB(Bbuf[0], 0);
  stageA(Abuf[1], 0, 64);
  stageA(Abuf[1], 1, 64);
  stageB(Bbuf[1], 64);
  if (t < 256) {
    yrow[t] = y[row0 + t];
    nAr[t] = ni[row0 + t];
  } else if (t < 384) {
    const int c = t - 256;
    ycol[c] = y[col0 + c];
    nBc[c] = nvp[col0 + c];
  }
  // drain tile 0's 3 stages; keep tile 1's 3 in flight
  asm volatile("s_waitcnt vmcnt(3) lgkmcnt(0)" ::: "memory");
  BAR();

  f32x16 acc[2][2] = {};
  i32x8 aF[2], bF;

// One K-tile = 2 phases. C: buffer of tile t (literal 0/1); K2: k-offset of
// tile t+2 (staged into buf C after its reads retire).
#define DO_TILE(C, K2)                                                         \
  do {                                                                         \
    /* ph0: read aF + bF0; MFMA col-block 0 */                                 \
    aF[0] = ldA(C, 0);                                                         \
    aF[1] = ldA(C, 1);                                                         \
    bF = ldB(C, 0);                                                            \
    BAR();                                                                     \
    __builtin_amdgcn_s_setprio(1);                                             \
    acc[0][0] = __builtin_amdgcn_mfma_scale_f32_32x32x64_f8f6f4(               \
        aF[0], bF, acc[0][0], 0, 0, 0, 0x7F7F7F7F, 0, 0x7F7F7F7F);             \
    acc[1][0] = __builtin_amdgcn_mfma_scale_f32_32x32x64_f8f6f4(               \
        aF[1], bF, acc[1][0], 0, 0, 0, 0x7F7F7F7F, 0, 0x7F7F7F7F);             \
    __builtin_amdgcn_s_setprio(0);                                             \
    BAR();                                                                     \
    /* ph1: read bF1; stage A(t+2) (A[C] barrier-retired); MFMA col 1 */       \
    bF = ldB(C, 1);                                                            \
    stageA(Abuf[C], 0, (K2));                                                  \
    stageA(Abuf[C], 1, (K2));                                                  \
    BAR();                                                                     \
    __builtin_amdgcn_s_setprio(1);                                             \
    acc[0][1] = __builtin_amdgcn_mfma_scale_f32_32x32x64_f8f6f4(               \
        aF[0], bF, acc[0][1], 0, 0, 0, 0x7F7F7F7F, 0, 0x7F7F7F7F);             \
    acc[1][1] = __builtin_amdgcn_mfma_scale_f32_32x32x64_f8f6f4(               \
        aF[1], bF, acc[1][1], 0, 0, 0, 0x7F7F7F7F, 0, 0x7F7F7F7F);             \
    __builtin_amdgcn_s_setprio(0);                                             \
    stageB(Bbuf[C], (K2));                                                     \
    asm volatile("s_waitcnt vmcnt(3)" ::: "memory");                           \
    BAR();                                                                     \
  } while (0)

  for (int kt = 0; kt < NT; kt += 2) {
    const int kb = ((kt + 2) & (NT - 1)) * 64;
    const int kc = ((kt + 3) & (NT - 1)) * 64;
    DO_TILE(0, kb);   // even tile lives in buf 0
    DO_TILE(1, kc);   // odd tile lives in buf 1
  }
#undef DO_TILE
  asm volatile("s_waitcnt vmcnt(0)" ::: "memory");

  // ---- epilogue: sq + mask; row-reduce -> loss_i, col-reduce -> loss_v ----
  // C/D 32x32: col = lane&31, row = (reg&3) + 8*(reg>>2) + 4*(lane>>5)
  const int rbase0 = row0;          // dir0: anchors i_f, indexed by row
  const int rbase1 = MDIM + col0;   // dir1: anchors v_f, indexed by col
  const float INF = __int_as_float(0x7F800000);

  float cs[2] = {0.0f, 0.0f};
  float cd[2] = {INF, INF};

#pragma unroll
  for (int R = 0; R < 2; ++R) {
#pragma unroll
    for (int g = 0; g < 16; ++g) {
      const int row_loc = wr * 64 + R * 32 + (g & 3) + 8 * (g >> 2) + 4 * hi;
      const float na = nAr[row_loc];
      const int yl = yrow[row_loc];
      float smax = 0.0f;
      float dmin = INF;
#pragma unroll
      for (int Cb = 0; Cb < 2; ++Cb) {
        const int col_loc = wc * 64 + Cb * 32 + l32;
        const float sq = fmaxf(na + nBc[col_loc] - 2.0f * acc[R][Cb][g], 0.0f);
        if (ycol[col_loc] == yl) {
          smax = fmaxf(smax, sq);
          cs[Cb] = fmaxf(cs[Cb], sq);
        } else {
          dmin = fminf(dmin, sq);
          cd[Cb] = fminf(cd[Cb], sq);
        }
      }
#pragma unroll
      for (int off = 1; off < 32; off <<= 1) {   // reduce within 32-lane half
        smax = fmaxf(smax, __shfl_xor(smax, off));
        dmin = fminf(dmin, __shfl_xor(dmin, off));
      }
      if (l32 == g) {   // spread atomics; both hi-halves own distinct rows
        // nonneg floats: int compare == float compare -> order-independent
        atomicMax(&same_sq[rbase0 + row_loc], __float_as_int(smax));
        atomicMin(&diff_sq[rbase0 + row_loc], __float_as_int(dmin));
      }
    }
  }
  // col reduce: merge hi-halves (rows of each half), lanes hi==0 publish
#pragma unroll
  for (int Cb = 0; Cb < 2; ++Cb) {
    float s = cs[Cb], d = cd[Cb];
    s = fmaxf(s, __shfl_xor(s, 32));
    d = fminf(d, __shfl_xor(d, 32));
    if (hi == 0) {
      const int col_loc = wc * 64 + Cb * 32 + l32;
      atomicMax(&same_sq[rbase1 + col_loc], __float_as_int(s));
      atomicMin(&diff_sq[rbase1 + col_loc], __float_as_int(d));
    }
  }
}

// --- finalize: sqrt, relu, sum ---------------------------------------------
__global__ __launch_bounds__(256) void finalize_kernel(
    const int* __restrict__ same_sq, const int* __restrict__ diff_sq,
    float* __restrict__ out) {
  const int i = blockIdx.x * 256 + threadIdx.x;  // 8192 total
  const float sm = sqrtf(__int_as_float(same_sq[i]));
  const float dm = sqrtf(__int_as_float(diff_sq[i]));  // +inf if no diff label
  float l = fmaxf(sm - dm + 1.2f, 0.0f);
  for (int off = 32; off; off >>= 1) l += __shfl_down(l, off);
  __shared__ float part[4];
  const int w = threadIdx.x >> 6, lane = threadIdx.x & 63;
  if (lane == 0) part[w] = l;
  __syncthreads();
  if (threadIdx.x == 0) atomicAdd(out, part[0] + part[1] + part[2] + part[3]);
}

extern "C" void kernel_launch(void* const* d_in, const int* in_sizes, int n_in,
                              void* d_out, int out_size, void* d_ws, size_t ws_size,
                              hipStream_t stream) {
  const float* vf = (const float*)d_in[0];
  const float* iff = (const float*)d_in[1];
  const int* y = (const int*)d_in[2];
  float* out = (float*)d_out;

  char* ws = (char*)d_ws;
  unsigned char* vb8 = (unsigned char*)ws;                        // 4 MB
  unsigned char* ib8 = (unsigned char*)(ws + (4u << 20));         // 4 MB
  float* nv  = (float*)(ws + (8u << 20));
  float* ni  = nv + 4096;
  float* nvp = nv + 2 * 4096;
  int* same_sq = (int*)(nv + 4 * 4096);                           // [2][4096]
  int* diff_sq = same_sq + 2 * 4096;                              // [2][4096]

  prep_kernel<<<2048, 256, 0, stream>>>(vf, iff, vb8, ib8, ni, nvp,
                                        same_sq, diff_sq, out);
  tri_gemm<<<dim3(32, 16), 512, 0, stream>>>(vb8, ib8, ni, nvp, y,
                                             same_sq, diff_sq);
  finalize_kernel<<<32, 256, 0, stream>>>(same_sq, diff_sq, out);
}